// Round 7
// baseline (297.919 us; speedup 1.0000x reference)
//
#include <hip/hip_runtime.h>
#include <math.h>

#define BATCH 128
#define NANCH 8400
#define NMSK  300
#define KPT   17
#define OUTC  56    // 4 box + 1 score + 34 kpt + 17 vis
#define CAND  1024  // candidate slots (>=300 + 13-bit-bin tie margin)
#define NTHR  1024
#define NBIN  8192  // 13-bit bins: top bits of positive f32 (monotone)
#define BSHIFT 19
#define NGRP  (NANCH / 4)   // 2100 uint4 groups
#define HPAD(i) ((i) + ((i) >> 3))   // pad 1 word per 8 -> lane stride 9 (coprime 32)
#define HSZ   (NBIN + NBIN / 8)      // 9216 words

__device__ __forceinline__ void prior_of(int i, float& stride, float& cx, float& cy) {
    int row, col;
    if (i < 6400)      { stride = 8.0f;  row = i / 80;              col = i - row * 80; }
    else if (i < 8000) { int ii = i - 6400; stride = 16.0f; row = ii / 40; col = ii - row * 40; }
    else               { int ii = i - 8000; stride = 32.0f; row = ii / 20; col = ii - row * 20; }
    cx = ((float)col + 0.5f) * stride;
    cy = ((float)row + 0.5f) * stride;
}

// ---------------------------------------------------------------------------
// Single launch, 128 blocks x 1024 (one block per batch).
// R7 changes vs R6 (structure identical, absmax 0.0 verified):
//  1. __launch_bounds__(1024, 4): R6 shipped with VGPR_Count=20 -> the sck[12]
//     score array was SPILLED to scratch (needs ~35+ live VGPRs). 2nd arg =
//     min waves/EU; 4 waves/EU == our actual shape (1 block/CU), lifting the
//     VGPR cap to ~512 so sck + greedy mask words stay in registers.
//  2. Padded histogram (idx + idx/8): suffix-scan read was 2x uint4 at 32B
//     lane stride = 16-way bank conflict (R6: 142K conflict cycles, R5: 730K).
//     Lane stride 9 words is coprime to 32 banks -> conflict-free b32 reads.
// All math bit-exact-verified in prior rounds (absmax 0.0): score f64-exp
// formula (R2/R3), histogram select + readlane scan (R4/R5/R6), kpt with
// recomputed priors (R4/R6). d_ws unused (poison fill unconditional anyway).
// ---------------------------------------------------------------------------
__global__ __launch_bounds__(NTHR, 4) void fused_kernel(
    const float* __restrict__ cls, const float* __restrict__ obj,
    const float* __restrict__ bbox, const float* __restrict__ kofs,
    const float* __restrict__ kvis, float* __restrict__ out)
{
    const int b    = blockIdx.x;
    const int tid  = threadIdx.x;
    const int lane = tid & 63;
    const int wv   = tid >> 6;

    __shared__ __align__(16) unsigned int hist[HSZ];     // 36864 B
    __shared__ unsigned int wtot[16], wab[16];
    __shared__ unsigned int sh_pivot, sh_cnt;
    __shared__ unsigned long long ckey[CAND];            // 8192 B
    __shared__ float bx1[NMSK], by1[NMSK], bx2[NMSK], by2[NMSK], area[NMSK];
    __shared__ float sval[NMSK];
    __shared__ int   sidx[NMSK];
    __shared__ unsigned long long supl[NMSK * 6];        // 14400 B
    __shared__ unsigned long long keepw[5];

    // ---- phase 1: scores into registers (bit-exact f64 exp) + zero hist ----
    unsigned int sck[12];   // 3 uint4 groups x 4 keys; static indexing only
    {
        const float4* c4 = (const float4*)(cls + (size_t)b * NANCH);
        const float4* o4 = (const float4*)(obj + (size_t)b * NANCH);
        #pragma unroll
        for (int k = 0; k < 3; ++k) {
            int g = tid + k * NTHR;
            if (g < NGRP) {
                float4 cv = c4[g];
                float4 ov = o4[g];
                float sa0 = 1.0f / (1.0f + (float)exp(-(double)cv.x));
                float sa1 = 1.0f / (1.0f + (float)exp(-(double)cv.y));
                float sa2 = 1.0f / (1.0f + (float)exp(-(double)cv.z));
                float sa3 = 1.0f / (1.0f + (float)exp(-(double)cv.w));
                float so0 = 1.0f / (1.0f + (float)exp(-(double)ov.x));
                float so1 = 1.0f / (1.0f + (float)exp(-(double)ov.y));
                float so2 = 1.0f / (1.0f + (float)exp(-(double)ov.z));
                float so3 = 1.0f / (1.0f + (float)exp(-(double)ov.w));
                sck[4 * k + 0] = __float_as_uint(sa0 * so0);
                sck[4 * k + 1] = __float_as_uint(sa1 * so1);
                sck[4 * k + 2] = __float_as_uint(sa2 * so2);
                sck[4 * k + 3] = __float_as_uint(sa3 * so3);
            } else {
                sck[4 * k + 0] = 0u; sck[4 * k + 1] = 0u;
                sck[4 * k + 2] = 0u; sck[4 * k + 3] = 0u;
            }
        }
        #pragma unroll
        for (int k = 0; k < 9; ++k) {
            int i = tid + k * NTHR;
            if (i < HSZ) hist[i] = 0u;
        }
        if (tid == 0) sh_cnt = 0u;
    }
    __syncthreads();

    // ---- phase 2: 8192-bin histogram from registers (padded indexing) ----
    #pragma unroll
    for (int k = 0; k < 3; ++k) {
        int g = tid + k * NTHR;
        if (g < NGRP) {
            atomicAdd(&hist[HPAD(sck[4 * k + 0] >> BSHIFT)], 1u);
            atomicAdd(&hist[HPAD(sck[4 * k + 1] >> BSHIFT)], 1u);
            atomicAdd(&hist[HPAD(sck[4 * k + 2] >> BSHIFT)], 1u);
            atomicAdd(&hist[HPAD(sck[4 * k + 3] >> BSHIFT)], 1u);
        }
    }
    __syncthreads();

    // ---- phase 3: suffix scan; thread owns bins [8t, 8t+8) ----
    // padded read: word 9t+k, lane stride 9 coprime 32 -> conflict-free
    unsigned int s7[8];
    {
        unsigned int hh[8];
        #pragma unroll
        for (int k = 0; k < 8; ++k) hh[k] = hist[9 * tid + k];
        s7[7] = hh[7];
        s7[6] = s7[7] + hh[6]; s7[5] = s7[6] + hh[5]; s7[4] = s7[5] + hh[4];
        s7[3] = s7[4] + hh[3]; s7[2] = s7[3] + hh[2]; s7[1] = s7[2] + hh[1];
        s7[0] = s7[1] + hh[0];
    }
    unsigned int T = s7[0];
    unsigned int v = T;
    #pragma unroll
    for (int d = 1; d < 64; d <<= 1) {
        unsigned int t2 = (unsigned int)__shfl_down((int)v, d, 64);
        if (lane + d < 64) v += t2;       // inclusive suffix over lanes >= lane
    }
    unsigned int aiw = v - T;             // sum over lanes > lane
    if (lane == 0) wtot[wv] = v;
    __syncthreads();
    if (tid < 16) {
        unsigned int wa = 0;
        for (int q = tid + 1; q < 16; ++q) wa += wtot[q];
        wab[tid] = wa;                    // sum over waves > w
    }
    __syncthreads();

    // ---- phase 4: LOCAL pivot detection (no suf write-back) ----
    {
        unsigned int ag = wab[wv] + aiw;
        #pragma unroll
        for (int k = 0; k < 8; ++k) {
            unsigned int ge = ag + s7[k];
            unsigned int gn = (k < 7) ? (ag + s7[k + 1]) : ag;
            if (ge >= NMSK && gn < NMSK) sh_pivot = 8u * (unsigned)tid + (unsigned)k;
        }
    }
    __syncthreads();
    unsigned int pivot_bits = sh_pivot << BSHIFT;

    // ---- phase 5: compact from registers (wave-aggregated counter) ----
    #pragma unroll
    for (int k = 0; k < 3; ++k) {
        int g = tid + k * NTHR;
        bool valid = (g < NGRP);
        #pragma unroll
        for (int s = 0; s < 4; ++s) {
            unsigned int key = sck[4 * k + s];
            bool pred = valid && (key >= pivot_bits);
            unsigned long long m = __ballot(pred);
            unsigned int cnt = (unsigned int)__popcll(m);
            unsigned int wbase = 0u;
            if (lane == 0 && cnt) wbase = atomicAdd(&sh_cnt, cnt);
            wbase = (unsigned int)__shfl((int)wbase, 0, 64);
            if (pred) {
                unsigned int p = wbase + (unsigned int)__popcll(m & ((1ull << lane) - 1ull));
                unsigned int idx = 4u * (unsigned)g + (unsigned)s;
                if (p < CAND)
                    ckey[p] = ((unsigned long long)key << 32)
                            | (unsigned long long)(0xFFFFFFFFu - idx);
            }
        }
    }
    __syncthreads();
    unsigned int M = sh_cnt; if (M > CAND) M = CAND;

    // ---- phase 6: rank order (score desc, idx asc) + FUSED box decode ----
    if (tid < (int)M) {
        unsigned long long mine = ckey[tid];
        int rank = 0;
        for (unsigned int t2 = 0; t2 < M; ++t2) rank += (ckey[t2] > mine) ? 1 : 0;
        if (rank < NMSK) {
            int i = (int)(0xFFFFFFFFu - (unsigned int)(mine & 0xFFFFFFFFull));
            sidx[rank] = i;
            sval[rank] = __uint_as_float((unsigned int)(mine >> 32));
            float stride, cx, cy;
            prior_of(i, stride, cx, cy);
            float4 bb = *(const float4*)(bbox + ((size_t)b * NANCH + (size_t)i) * 4);
            float x = bb.x * stride + cx;
            float y = bb.y * stride + cy;
            float w = expf(bb.z) * stride;
            float h = expf(bb.w) * stride;
            float x1 = x - 0.5f * w, y1 = y - 0.5f * h;
            float x2 = x + 0.5f * w, y2 = y + 0.5f * h;
            bx1[rank] = x1; by1[rank] = y1; bx2[rank] = x2; by2[rank] = y2;
            area[rank] = fmaxf(x2 - x1, 0.0f) * fmaxf(y2 - y1, 0.0f);
        }
    }
    __syncthreads();

    // ---- phase 7: suppression bitmask, task = (row i, word w) ----
    for (int t = tid; t < NMSK * 5; t += NTHR) {
        int w = t / NMSK;
        int i = t - w * NMSK;
        int jlo = w * 64; if (jlo < i + 1) jlo = i + 1;
        int jhi = w * 64 + 64; if (jhi > NMSK) jhi = NMSK;
        unsigned long long m = 0;
        float ax1 = bx1[i], ay1 = by1[i], ax2 = bx2[i], ay2 = by2[i], aa = area[i];
        for (int j = jlo; j < jhi; ++j) {
            float lx = fmaxf(ax1, bx1[j]);
            float ly = fmaxf(ay1, by1[j]);
            float rx = fminf(ax2, bx2[j]);
            float ry = fminf(ay2, by2[j]);
            float iw = fmaxf(rx - lx, 0.0f);
            float ih = fmaxf(ry - ly, 0.0f);
            float inter = iw * ih;
            float iou = inter / (aa + area[j] - inter + 1e-7f);
            if (iou > 0.65f) m |= 1ull << (j & 63);
        }
        supl[i * 6 + w] = m;
    }
    __syncthreads();

    // ---- phase 8: wave0 rolled readlane greedy || others kpt/vis+cols0-3 ----
    if (tid < 64) {
        int j = tid;
        unsigned long long keep0 = ~0ull, keep1 = ~0ull, keep2 = ~0ull, keep3 = ~0ull;
        unsigned long long keep4 = (1ull << (NMSK - 256)) - 1ull;
        // keepN stay wave-uniform (updated only via readlane) -> SGPR chain.
        #define CHUNK(C, KC, IMAX) { \
            int r = (C) * 64 + j; \
            unsigned int lo0=0,hi0=0,lo1=0,hi1=0,lo2=0,hi2=0,lo3=0,hi3=0,lo4=0,hi4=0; \
            if (r < NMSK) { \
                unsigned long long w0 = supl[r*6+0], w1 = supl[r*6+1], w2 = supl[r*6+2]; \
                unsigned long long w3 = supl[r*6+3], w4 = supl[r*6+4]; \
                lo0=(unsigned int)w0; hi0=(unsigned int)(w0>>32); \
                lo1=(unsigned int)w1; hi1=(unsigned int)(w1>>32); \
                lo2=(unsigned int)w2; hi2=(unsigned int)(w2>>32); \
                lo3=(unsigned int)w3; hi3=(unsigned int)(w3>>32); \
                lo4=(unsigned int)w4; hi4=(unsigned int)(w4>>32); } \
            _Pragma("clang loop unroll(disable)") \
            for (int bi = 0; bi < (IMAX); ++bi) { \
                if ((KC >> bi) & 1ull) { \
                    unsigned long long s0 = ((unsigned long long)__builtin_amdgcn_readlane(hi0,bi)<<32) | __builtin_amdgcn_readlane(lo0,bi); \
                    unsigned long long s1 = ((unsigned long long)__builtin_amdgcn_readlane(hi1,bi)<<32) | __builtin_amdgcn_readlane(lo1,bi); \
                    unsigned long long s2 = ((unsigned long long)__builtin_amdgcn_readlane(hi2,bi)<<32) | __builtin_amdgcn_readlane(lo2,bi); \
                    unsigned long long s3 = ((unsigned long long)__builtin_amdgcn_readlane(hi3,bi)<<32) | __builtin_amdgcn_readlane(lo3,bi); \
                    unsigned long long s4 = ((unsigned long long)__builtin_amdgcn_readlane(hi4,bi)<<32) | __builtin_amdgcn_readlane(lo4,bi); \
                    keep0 &= ~s0; keep1 &= ~s1; keep2 &= ~s2; keep3 &= ~s3; keep4 &= ~s4; } } }
        CHUNK(0, keep0, 64)
        CHUNK(1, keep1, 64)
        CHUNK(2, keep2, 64)
        CHUNK(3, keep3, 64)
        CHUNK(4, keep4, NMSK - 256)
        #undef CHUNK
        if (j == 0) { keepw[0]=keep0; keepw[1]=keep1; keepw[2]=keep2; keepw[3]=keep3; keepw[4]=keep4; }
    } else {
        const float* kof = kofs + (size_t)b * NANCH * 34;
        const float* kvi = kvis + (size_t)b * NANCH * KPT;
        float* ob = out + (size_t)b * NMSK * OUTC;
        // cols 0..3 from LDS box arrays
        for (int t = tid - 64; t < NMSK * 4; t += NTHR - 64) {
            int j = t >> 2, ci = t & 3;
            float vv = (ci == 0) ? bx1[j] : (ci == 1) ? by1[j] : (ci == 2) ? bx2[j] : by2[j];
            ob[j * OUTC + ci] = vv;
        }
        // cols 5..55: gathered kpt decode (priors recomputed) + vis sigmoid
        for (int e = tid - 64; e < NMSK * 51; e += NTHR - 64) {
            int j  = e / 51;
            int ci = e - j * 51;
            int i  = sidx[j];
            float vv;
            if (ci < 34) {
                float stride, cx, cy;
                prior_of(i, stride, cx, cy);
                float off = kof[(size_t)i * 34 + ci];
                vv = off * stride + ((ci & 1) ? cy : cx);
            } else {
                float x = kvi[(size_t)i * KPT + (ci - 34)];
                vv = 1.0f / (1.0f + expf(-x));
            }
            ob[j * OUTC + 5 + ci] = vv;
        }
    }
    __syncthreads();

    // ---- phase 9: col 4 (keep-masked score) ----
    if (tid < NMSK) {
        bool kp = (keepw[tid >> 6] >> (tid & 63)) & 1ull;
        out[(size_t)b * NMSK * OUTC + (size_t)tid * OUTC + 4] = kp ? sval[tid] : 0.0f;
    }
}

// ---------------------------------------------------------------------------
extern "C" void kernel_launch(void* const* d_in, const int* in_sizes, int n_in,
                              void* d_out, int out_size, void* d_ws, size_t ws_size,
                              hipStream_t stream) {
    const float* cls  = (const float*)d_in[0];  // [B,N,1]
    const float* bbox = (const float*)d_in[1];  // [B,N,4]
    const float* obj  = (const float*)d_in[2];  // [B,N]
    const float* kofs = (const float*)d_in[3];  // [B,N,17,2]
    const float* kvis = (const float*)d_in[4];  // [B,N,17]
    float* out = (float*)d_out;                 // [B,300,56]

    (void)d_ws; (void)ws_size;  // poison fill is unconditional; single launch

    fused_kernel<<<BATCH, NTHR, 0, stream>>>(cls, obj, bbox, kofs, kvis, out);
}